// Round 2
// baseline (650.015 us; speedup 1.0000x reference)
//
#include <hip/hip_runtime.h>

// CodebookQuantizer: out[q] = softmax_k( (2*h[q].cb[k] - |cb[k]|^2) / T ) @ cb
// B*Q = 16384 rows, D = 512, K = 8192, T = 0.1. Output fp32 (== z_e forward).
//
// bf16 MFMA scan finds candidate codes (threshold = wave-shared running max
// - 40 log2 units; bf16 dot noise sigma ~2 log2 units -> miss prob ~0);
// exact fp32 epilogue recomputes candidate logits, softmax, and gathers.

typedef short  bf16x8 __attribute__((ext_vector_type(8)));
typedef float  f32x4  __attribute__((ext_vector_type(4)));

#define BQ      64            // query rows per block
#define KC      32            // codebook rows per chunk
#define DD      512
#define NCODES  8192
#define NCHUNK  (NCODES / KC) // 256
#define KSTEPS  (DD / 32)     // 16 MFMA k-steps
#define CAP     128           // candidate list capacity per row
#define TH2     40.0f         // append threshold (log2 units below running max)

// 2/T * log2(e), 1/T * log2(e)
#define SC_CROSS 28.853900817779268f
#define SC_ESQ   14.426950408889634f

static __device__ __forceinline__ unsigned short f2bf(float x) {
    // round-to-nearest-even float -> bf16 bits (inputs are finite)
    unsigned int u = __float_as_uint(x);
    u += 0x7fffu + ((u >> 16) & 1u);
    return (unsigned short)(u >> 16);
}

__global__ __launch_bounds__(512, 2)
void vq_scan_kernel(const float* __restrict__ h,
                    const float* __restrict__ cb,
                    float* __restrict__ out)
{
    // swizzled bf16 codebook chunk: sC[row][unit ^ (row&7)], unit = 8 bf16 = 16B
    __shared__ __align__(16) unsigned short sC[KC * DD];   // 32 KB
    __shared__ __align__(16) float sEsq[KC];
    __shared__ int   sCnt[BQ];
    __shared__ float sMax[BQ][2];                          // per-row scan max, per rowtile-wave
    __shared__ int   sListC[BQ][CAP];                      // 32 KB

    const int tid  = threadIdx.x;
    const int w    = tid >> 6;        // wave 0..7
    const int lane = tid & 63;
    const int pair = w >> 1;          // q-slice owner (16 rows each)
    const int rt   = w & 1;           // code rowtile within chunk (16 codes)
    const int qb   = blockIdx.x * BQ;

    if (tid < BQ) sCnt[tid] = 0;

    // ---- H B-fragments (bf16), persistent in registers ----
    // B-frag for mfma_f32_16x16x32_bf16: lane holds B[k=(lane>>4)*8+j][col=lane&15]
    const int qrow = qb + pair * 16 + (lane & 15);
    const int dsub = (lane >> 4) * 8;
    bf16x8 hfrag[KSTEPS];
#pragma unroll
    for (int k = 0; k < KSTEPS; ++k) {
        const float* src = h + (size_t)qrow * DD + k * 32 + dsub;
        float4 a = *reinterpret_cast<const float4*>(src);
        float4 b = *reinterpret_cast<const float4*>(src + 4);
        bf16x8 f;
        f[0] = (short)f2bf(a.x); f[1] = (short)f2bf(a.y);
        f[2] = (short)f2bf(a.z); f[3] = (short)f2bf(a.w);
        f[4] = (short)f2bf(b.x); f[5] = (short)f2bf(b.y);
        f[6] = (short)f2bf(b.z); f[7] = (short)f2bf(b.w);
        hfrag[k] = f;
    }

    // ---- staging prefetch: wave w owns chunk rows [w*4, w*4+4) ----
    const int myrow = w * 4;
    float pre[4][8];
#pragma unroll
    for (int r = 0; r < 4; ++r) {
        const float* src = cb + (size_t)(myrow + r) * DD + lane * 8;
        *reinterpret_cast<float4*>(&pre[r][0]) = *reinterpret_cast<const float4*>(src);
        *reinterpret_cast<float4*>(&pre[r][4]) = *reinterpret_cast<const float4*>(src + 4);
    }

    float mrun = -1e38f;                              // wave-shared running max (log2 logits)
    const int ql     = pair * 16 + (lane & 15);       // local q row this lane appends for
    const int crow   = rt * 16 + (lane & 15);         // A-frag code row within chunk
    const int clocal = rt * 16 + (lane >> 4) * 4;     // first of this lane's 4 result codes
    const int swz    = crow & 7;
    const int ub     = lane >> 4;

    for (int t = 0; t < NCHUNK; ++t) {
        // ---- write phase: convert prefetched fp32 rows -> swizzled bf16 + e_sq ----
#pragma unroll
        for (int r = 0; r < 4; ++r) {
            const int row = myrow + r;
            float s2 = 0.f;
#pragma unroll
            for (int j = 0; j < 8; ++j) s2 += pre[r][j] * pre[r][j];
#pragma unroll
            for (int off = 32; off > 0; off >>= 1) s2 += __shfl_xor(s2, off);
            if (lane == 0) sEsq[row] = s2;
            bf16x8 v;
#pragma unroll
            for (int j = 0; j < 8; ++j) v[j] = (short)f2bf(pre[r][j]);
            const int u = lane ^ (row & 7);
            *reinterpret_cast<bf16x8*>(&sC[row * DD + u * 8]) = v;
        }
        // ---- prefetch next chunk (overlaps with scan below) ----
        if (t + 1 < NCHUNK) {
#pragma unroll
            for (int r = 0; r < 4; ++r) {
                const float* src = cb + (size_t)((t + 1) * KC + myrow + r) * DD + lane * 8;
                *reinterpret_cast<float4*>(&pre[r][0]) = *reinterpret_cast<const float4*>(src);
                *reinterpret_cast<float4*>(&pre[r][4]) = *reinterpret_cast<const float4*>(src + 4);
            }
        }
        __syncthreads();

        // ---- scan phase: S^T = C_chunk . H^T via MFMA, threshold + append ----
        f32x4 acc0 = {0.f, 0.f, 0.f, 0.f};
        f32x4 acc1 = {0.f, 0.f, 0.f, 0.f};
#pragma unroll
        for (int k = 0; k < KSTEPS; k += 2) {
            bf16x8 a0 = *reinterpret_cast<const bf16x8*>(
                &sC[crow * DD + (((k    ) * 4 + ub) ^ swz) * 8]);
            bf16x8 a1 = *reinterpret_cast<const bf16x8*>(
                &sC[crow * DD + (((k + 1) * 4 + ub) ^ swz) * 8]);
            acc0 = __builtin_amdgcn_mfma_f32_16x16x32_bf16(a0, hfrag[k],     acc0, 0, 0, 0);
            acc1 = __builtin_amdgcn_mfma_f32_16x16x32_bf16(a1, hfrag[k + 1], acc1, 0, 0, 0);
        }
        // D layout: row(code) = (lane>>4)*4 + r, col(q) = lane&15
        f32x4 esq4 = *reinterpret_cast<const f32x4*>(&sEsq[clocal]);
        float Lv[4];
#pragma unroll
        for (int r = 0; r < 4; ++r)
            Lv[r] = (acc0[r] + acc1[r]) * SC_CROSS - esq4[r] * SC_ESQ;

        // wave-level row max: share across the 4 lanes owning this q column
        float mloc = fmaxf(fmaxf(Lv[0], Lv[1]), fmaxf(Lv[2], Lv[3]));
        mloc = fmaxf(mloc, __shfl_xor(mloc, 16));
        mloc = fmaxf(mloc, __shfl_xor(mloc, 32));
        const float mnew = fmaxf(mrun, mloc);
        const float thr  = mnew - TH2;
        if (Lv[0] > thr || Lv[1] > thr || Lv[2] > thr || Lv[3] > thr) {
#pragma unroll
            for (int r = 0; r < 4; ++r) {
                if (Lv[r] > thr) {
                    int idx = atomicAdd(&sCnt[ql], 1);
                    if (idx < CAP) sListC[ql][idx] = t * KC + clocal + r;
                }
            }
        }
        mrun = mnew;
        __syncthreads();
    }

    // publish per-row scan max (all 4 owning lanes agree; lane<16 writes)
    if (ub == 0) sMax[ql][rt] = mrun;
    __syncthreads();

    // ---- epilogue: exact fp32 logits for candidates, online softmax gather ----
    const int l8 = lane * 8;
#pragma unroll 1
    for (int i = 0; i < 8; ++i) {
        const int q_loc = w * 8 + i;
        const int qg    = qb + q_loc;
        const int n     = min(sCnt[q_loc], CAP);
        const float Mest = fmaxf(sMax[q_loc][0], sMax[q_loc][1]);

        float hreg[8];
        const float* hp = h + (size_t)qg * DD + l8;
#pragma unroll
        for (int j = 0; j < 8; ++j) hreg[j] = hp[j];

        float lsum = 0.f;
        float acc[8] = {0.f, 0.f, 0.f, 0.f, 0.f, 0.f, 0.f, 0.f};
#pragma unroll 1
        for (int jj = 0; jj < n; ++jj) {
            const int code = sListC[q_loc][jj];
            const float* cp = cb + (size_t)code * DD + l8;
            float c[8];
            float dot = 0.f, s2 = 0.f;
#pragma unroll
            for (int j = 0; j < 8; ++j) {
                c[j] = cp[j];
                dot += hreg[j] * c[j];
                s2  += c[j] * c[j];
            }
#pragma unroll
            for (int off = 32; off > 0; off >>= 1) {
                dot += __shfl_xor(dot, off);
                s2  += __shfl_xor(s2,  off);
            }
            const float Lj = dot * SC_CROSS - s2 * SC_ESQ;   // exact log2-logit
            const float wj = exp2f(Lj - Mest);               // Mest within ~8 of true max
            lsum += wj;
#pragma unroll
            for (int j = 0; j < 8; ++j) acc[j] = fmaf(wj, c[j], acc[j]);
        }
        const float inv = 1.0f / lsum;

        float* op = out + (size_t)qg * DD + l8;
        float4 o0 = {acc[0] * inv, acc[1] * inv, acc[2] * inv, acc[3] * inv};
        float4 o1 = {acc[4] * inv, acc[5] * inv, acc[6] * inv, acc[7] * inv};
        *reinterpret_cast<float4*>(op)     = o0;
        *reinterpret_cast<float4*>(op + 4) = o1;
    }
}

extern "C" void kernel_launch(void* const* d_in, const int* in_sizes, int n_in,
                              void* d_out, int out_size, void* d_ws, size_t ws_size,
                              hipStream_t stream) {
    const float* h  = (const float*)d_in[0];   // (4*4096, 512) fp32
    const float* cb = (const float*)d_in[1];   // (8192, 512) fp32
    float* out = (float*)d_out;                // (4*4096, 512) fp32
    // 16384 rows / BQ(64) = 256 blocks, 512 threads (8 waves)
    vq_scan_kernel<<<dim3(256), dim3(512), 0, stream>>>(h, cb, out);
}

// Round 3
// 385.013 us; speedup vs baseline: 1.6883x; 1.6883x over previous
//
#include <hip/hip_runtime.h>

// CodebookQuantizer: out[q] = softmax_k( (2*h[q].cb[k] - |cb[k]|^2) / T ) @ cb
// B*Q = 16384, D = 512, K = 8192, T = 0.1. Output fp32 (z_e forward value).
//
// Kernel 1: convert codebook fp32 -> pre-swizzled bf16 (+ e_sq) in d_ws, once.
// Kernel 2: bf16 MFMA scan (global_load_lds staged, double-buffered LDS) finds
// candidates within 40 log2-units of a running max; exact fp32 epilogue
// recomputes candidate logits, softmax, gather.

typedef short  bf16x8 __attribute__((ext_vector_type(8)));
typedef float  f32x4  __attribute__((ext_vector_type(4)));

#define BQ      64            // query rows per block
#define KC      64            // codebook rows per chunk
#define DD      512
#define NCODES  8192
#define NCHUNK  (NCODES / KC) // 128
#define KSTEPS  (DD / 32)     // 16 MFMA k-steps
#define CAP     64            // candidate list capacity per row
#define TH2     40.0f         // append threshold (log2 units below running max)

// 2/T * log2(e), 1/T * log2(e)
#define SC_CROSS 28.853900817779268f
#define SC_ESQ   14.426950408889634f

static __device__ __forceinline__ unsigned short f2bf(float x) {
    unsigned int u = __float_as_uint(x);
    u += 0x7fffu + ((u >> 16) & 1u);
    return (unsigned short)(u >> 16);
}

static __device__ __forceinline__ void gload_lds16(const void* g, void* l) {
    __builtin_amdgcn_global_load_lds(
        (const __attribute__((address_space(1))) unsigned int*)g,
        (__attribute__((address_space(3))) unsigned int*)l, 16, 0, 0);
}
static __device__ __forceinline__ void gload_lds4(const void* g, void* l) {
    __builtin_amdgcn_global_load_lds(
        (const __attribute__((address_space(1))) unsigned int*)g,
        (__attribute__((address_space(3))) unsigned int*)l, 4, 0, 0);
}

// ---------------- kernel 1: codebook -> pre-swizzled bf16 + e_sq ----------------
__global__ __launch_bounds__(256)
void vq_convert_kernel(const float* __restrict__ cb,
                       unsigned short* __restrict__ cbswz,
                       float* __restrict__ esq)
{
    const int w     = threadIdx.x >> 6;
    const int lane  = threadIdx.x & 63;
    const int rbase = blockIdx.x * 32 + w * 8;
#pragma unroll 1
    for (int i = 0; i < 8; ++i) {
        const int r = rbase + i;
        const float* src = cb + (size_t)r * DD + lane * 8;
        float4 a = *reinterpret_cast<const float4*>(src);
        float4 b = *reinterpret_cast<const float4*>(src + 4);
        float v[8] = {a.x, a.y, a.z, a.w, b.x, b.y, b.z, b.w};
        float s2 = 0.f;
        bf16x8 o;
#pragma unroll
        for (int j = 0; j < 8; ++j) { s2 += v[j] * v[j]; o[j] = (short)f2bf(v[j]); }
#pragma unroll
        for (int off = 32; off > 0; off >>= 1) s2 += __shfl_xor(s2, off);
        const int u = lane ^ (r & 7);   // pre-swizzle: linear LDS copy yields swizzled tile
        *reinterpret_cast<bf16x8*>(cbswz + (size_t)r * DD + u * 8) = o;
        if (lane == 0) esq[r] = s2;
    }
}

// ---------------- kernel 2: scan + exact epilogue ----------------
__global__ __launch_bounds__(512, 2)
void vq_scan_kernel(const float* __restrict__ h,
                    const float* __restrict__ cb,
                    const unsigned short* __restrict__ cbswz,
                    const float* __restrict__ esqg,
                    float* __restrict__ out)
{
    __shared__ __align__(16) unsigned short sC[2][KC * DD];  // 128 KB dbuf
    __shared__ __align__(16) float sEsq[2][KC];
    __shared__ int   sCnt[BQ];
    __shared__ float sMax[BQ][4];
    __shared__ int   sListC[BQ][CAP];                        // 16 KB

    const int tid  = threadIdx.x;
    const int w    = tid >> 6;        // wave 0..7
    const int lane = tid & 63;
    const int rt   = w & 3;           // rowtile: 16 codes within chunk
    const int qs   = w >> 2;          // q-slice: 32 q rows
    const int qb   = blockIdx.x * BQ;

    if (tid < BQ) sCnt[tid] = 0;

    // ---- H B-fragments (bf16), two 16-col halves of the 32-q slice ----
    // B-frag of mfma_f32_16x16x32_bf16: lane holds B[k=(lane>>4)*8+j][col=lane&15]
    const int c16   = lane & 15;
    const int ub    = lane >> 4;
    const int qrowA = qb + qs * 32 + c16;
    const int dsub  = ub * 8;
    bf16x8 hfA[KSTEPS], hfB[KSTEPS];
#pragma unroll
    for (int k = 0; k < KSTEPS; ++k) {
        const float* sA = h + (size_t)qrowA * DD + k * 32 + dsub;
        const float* sB = sA + (size_t)16 * DD;
        float4 a0 = *reinterpret_cast<const float4*>(sA);
        float4 a1 = *reinterpret_cast<const float4*>(sA + 4);
        float4 b0 = *reinterpret_cast<const float4*>(sB);
        float4 b1 = *reinterpret_cast<const float4*>(sB + 4);
        bf16x8 fa, fb;
        fa[0] = (short)f2bf(a0.x); fa[1] = (short)f2bf(a0.y);
        fa[2] = (short)f2bf(a0.z); fa[3] = (short)f2bf(a0.w);
        fa[4] = (short)f2bf(a1.x); fa[5] = (short)f2bf(a1.y);
        fa[6] = (short)f2bf(a1.z); fa[7] = (short)f2bf(a1.w);
        fb[0] = (short)f2bf(b0.x); fb[1] = (short)f2bf(b0.y);
        fb[2] = (short)f2bf(b0.z); fb[3] = (short)f2bf(b0.w);
        fb[4] = (short)f2bf(b1.x); fb[5] = (short)f2bf(b1.y);
        fb[6] = (short)f2bf(b1.z); fb[7] = (short)f2bf(b1.w);
        hfA[k] = fa; hfB[k] = fb;
    }

    // ---- prologue: stage chunk 0 into buf 0 ----
    {
        const char* gc = (const char*)cbswz;
#pragma unroll
        for (int r = 0; r < 8; ++r)
            gload_lds16(gc + r * 8192 + w * 1024 + lane * 16,
                        (char*)&sC[0][0] + r * 8192 + w * 1024);
        if (w == 0)
            gload_lds4((const char*)esqg + lane * 4, (char*)&sEsq[0][0]);
    }
    __syncthreads();   // drains vmcnt + covers sCnt init

    float mrunA = -1e38f, mrunB = -1e38f;
    const int qlA    = qs * 32 + c16;
    const int qlB    = qlA + 16;
    const int crow   = rt * 16 + c16;
    const int swz    = crow & 7;
    const int clocal = rt * 16 + ub * 4;
    int cur = 0;

    for (int t = 0; t < NCHUNK; ++t) {
        // issue next-chunk staging first (overlaps with compute below)
        if (t + 1 < NCHUNK) {
            const char* gc = (const char*)cbswz + (size_t)(t + 1) * (KC * DD * 2);
#pragma unroll
            for (int r = 0; r < 8; ++r)
                gload_lds16(gc + r * 8192 + w * 1024 + lane * 16,
                            (char*)&sC[cur ^ 1][0] + r * 8192 + w * 1024);
            if (w == 0)
                gload_lds4((const char*)(esqg + (t + 1) * KC) + lane * 4,
                           (char*)&sEsq[cur ^ 1][0]);
        }

        // ---- scan: S^T = C_rowtile . H^T, A-frag shared by both q halves ----
        const unsigned short* cbase = &sC[cur][crow * DD];
        f32x4 accA0 = {0.f,0.f,0.f,0.f}, accA1 = {0.f,0.f,0.f,0.f};
        f32x4 accB0 = {0.f,0.f,0.f,0.f}, accB1 = {0.f,0.f,0.f,0.f};
#pragma unroll
        for (int k = 0; k < KSTEPS; k += 2) {
            bf16x8 a0 = *reinterpret_cast<const bf16x8*>(&cbase[(((k    ) * 4 + ub) ^ swz) * 8]);
            bf16x8 a1 = *reinterpret_cast<const bf16x8*>(&cbase[(((k + 1) * 4 + ub) ^ swz) * 8]);
            accA0 = __builtin_amdgcn_mfma_f32_16x16x32_bf16(a0, hfA[k],     accA0, 0, 0, 0);
            accB0 = __builtin_amdgcn_mfma_f32_16x16x32_bf16(a0, hfB[k],     accB0, 0, 0, 0);
            accA1 = __builtin_amdgcn_mfma_f32_16x16x32_bf16(a1, hfA[k + 1], accA1, 0, 0, 0);
            accB1 = __builtin_amdgcn_mfma_f32_16x16x32_bf16(a1, hfB[k + 1], accB1, 0, 0, 0);
        }

        // D layout: row(code) = ub*4 + r, col(q) = lane&15
        f32x4 e4 = *reinterpret_cast<const f32x4*>(&sEsq[cur][clocal]);
        float LvA[4], LvB[4];
#pragma unroll
        for (int r = 0; r < 4; ++r) {
            LvA[r] = (accA0[r] + accA1[r]) * SC_CROSS - e4[r] * SC_ESQ;
            LvB[r] = (accB0[r] + accB1[r]) * SC_CROSS - e4[r] * SC_ESQ;
        }
        float mA = fmaxf(fmaxf(LvA[0], LvA[1]), fmaxf(LvA[2], LvA[3]));
        float mB = fmaxf(fmaxf(LvB[0], LvB[1]), fmaxf(LvB[2], LvB[3]));
        mA = fmaxf(mA, __shfl_xor(mA, 16)); mA = fmaxf(mA, __shfl_xor(mA, 32));
        mB = fmaxf(mB, __shfl_xor(mB, 16)); mB = fmaxf(mB, __shfl_xor(mB, 32));
        mrunA = fmaxf(mrunA, mA);
        mrunB = fmaxf(mrunB, mB);
        const float thrA = mrunA - TH2, thrB = mrunB - TH2;
        if (LvA[0] > thrA || LvA[1] > thrA || LvA[2] > thrA || LvA[3] > thrA) {
#pragma unroll
            for (int r = 0; r < 4; ++r)
                if (LvA[r] > thrA) {
                    int idx = atomicAdd(&sCnt[qlA], 1);
                    if (idx < CAP) sListC[qlA][idx] = t * KC + clocal + r;
                }
        }
        if (LvB[0] > thrB || LvB[1] > thrB || LvB[2] > thrB || LvB[3] > thrB) {
#pragma unroll
            for (int r = 0; r < 4; ++r)
                if (LvB[r] > thrB) {
                    int idx = atomicAdd(&sCnt[qlB], 1);
                    if (idx < CAP) sListC[qlB][idx] = t * KC + clocal + r;
                }
        }

        __syncthreads();   // next-chunk DMA drained; buf[cur] reads complete
        cur ^= 1;
    }

    // publish per-(row, rowtile) scan max (all 4 ub lanes agree)
    if (ub == 0) { sMax[qlA][rt] = mrunA; sMax[qlB][rt] = mrunB; }
    __syncthreads();

    // ---- epilogue: exact fp32 logits for candidates, online softmax gather ----
    const int l8 = lane * 8;
#pragma unroll 1
    for (int i = 0; i < 8; ++i) {
        const int q_loc = w * 8 + i;
        const int qg    = qb + q_loc;
        const int n     = min(sCnt[q_loc], CAP);
        const float* mx = sMax[q_loc];
        const float Mest = fmaxf(fmaxf(mx[0], mx[1]), fmaxf(mx[2], mx[3]));

        float hreg[8];
        const float* hp = h + (size_t)qg * DD + l8;
#pragma unroll
        for (int j = 0; j < 8; ++j) hreg[j] = hp[j];

        float lsum = 0.f;
        float acc[8] = {0.f, 0.f, 0.f, 0.f, 0.f, 0.f, 0.f, 0.f};
#pragma unroll 1
        for (int jj = 0; jj < n; ++jj) {
            const int code = sListC[q_loc][jj];
            const float* cp = cb + (size_t)code * DD + l8;
            float c[8];
            float dot = 0.f, s2 = 0.f;
#pragma unroll
            for (int j = 0; j < 8; ++j) {
                c[j] = cp[j];
                dot += hreg[j] * c[j];
                s2  += c[j] * c[j];
            }
#pragma unroll
            for (int off = 32; off > 0; off >>= 1) {
                dot += __shfl_xor(dot, off);
                s2  += __shfl_xor(s2,  off);
            }
            const float Lj = dot * SC_CROSS - s2 * SC_ESQ;   // exact log2-logit
            const float wj = exp2f(Lj - Mest);
            lsum += wj;
#pragma unroll
            for (int j = 0; j < 8; ++j) acc[j] = fmaf(wj, c[j], acc[j]);
        }
        const float inv = 1.0f / lsum;

        float* op = out + (size_t)qg * DD + l8;
        float4 o0 = {acc[0] * inv, acc[1] * inv, acc[2] * inv, acc[3] * inv};
        float4 o1 = {acc[4] * inv, acc[5] * inv, acc[6] * inv, acc[7] * inv};
        *reinterpret_cast<float4*>(op)     = o0;
        *reinterpret_cast<float4*>(op + 4) = o1;
    }
}

extern "C" void kernel_launch(void* const* d_in, const int* in_sizes, int n_in,
                              void* d_out, int out_size, void* d_ws, size_t ws_size,
                              hipStream_t stream) {
    const float* h  = (const float*)d_in[0];   // (16384, 512) fp32
    const float* cb = (const float*)d_in[1];   // (8192, 512) fp32
    float* out = (float*)d_out;                // (16384, 512) fp32

    unsigned short* cbswz = (unsigned short*)d_ws;                       // 8 MB
    float* esq = (float*)((char*)d_ws + (size_t)NCODES * DD * 2);        // 32 KB

    vq_convert_kernel<<<dim3(NCODES / 32), dim3(256), 0, stream>>>(cb, cbswz, esq);
    vq_scan_kernel<<<dim3(256), dim3(512), 0, stream>>>(h, cb, cbswz, esq, out);
}

// Round 4
// 201.107 us; speedup vs baseline: 3.2322x; 1.9145x over previous
//
#include <hip/hip_runtime.h>

// CodebookQuantizer: out[q] = softmax_k( (2*h[q].cb[k] - |cb[k]|^2) / T ) @ cb
// B*Q = 16384, D = 512, K = 8192, T = 0.1. Output fp32 (z_e forward value).
//
// K1 convert: codebook fp32 -> pre-swizzled bf16 (+ exact e_sq) in d_ws.
// K2 scan:    256 blocks = 64 q-tiles x 4 codebook quarters. Each block scans
//             its 2 MB quarter (L2-resident per XCD via bid%8 round-robin) for
//             its 256 q rows with bf16 MFMA; appends candidates (approx logit
//             within TH2=52 of a stale running max) to per-(row,quarter) ring
//             lists in d_ws.
// K3 merge:   per q-row, merge 4 lists, prune at max-40 (survivors ~1.3),
//             exact fp32 recompute + online softmax + gather.

typedef short  bf16x8 __attribute__((ext_vector_type(8)));
typedef float  f32x4  __attribute__((ext_vector_type(4)));

#define BQ      256           // q rows per block
#define KC      64            // codebook rows per chunk
#define DD      512
#define NCODES  8192
#define NQUART  4
#define QCODES  (NCODES / NQUART)   // 2048
#define NCHUNK  (QCODES / KC)       // 32
#define CAP     16                  // ring-buffer capacity per (row, quarter)
#define TH2     52.0f               // scan append threshold (log2 units)
#define PRUNE   40.0f               // epilogue prune threshold (log2 units)

// 2/T * log2(e), 1/T * log2(e)
#define SC_CROSS 28.853900817779268f
#define SC_ESQ   14.426950408889634f

static __device__ __forceinline__ unsigned short f2bf(float x) {
    unsigned int u = __float_as_uint(x);
    u += 0x7fffu + ((u >> 16) & 1u);
    return (unsigned short)(u >> 16);
}

static __device__ __forceinline__ void gload_lds16(const void* g, void* l) {
    __builtin_amdgcn_global_load_lds(
        (const __attribute__((address_space(1))) unsigned int*)g,
        (__attribute__((address_space(3))) unsigned int*)l, 16, 0, 0);
}
static __device__ __forceinline__ void gload_lds4(const void* g, void* l) {
    __builtin_amdgcn_global_load_lds(
        (const __attribute__((address_space(1))) unsigned int*)g,
        (__attribute__((address_space(3))) unsigned int*)l, 4, 0, 0);
}

// ---------------- K1: codebook -> pre-swizzled bf16 + e_sq ----------------
__global__ __launch_bounds__(256)
void vq_convert_kernel(const float* __restrict__ cb,
                       unsigned short* __restrict__ cbswz,
                       float* __restrict__ esq)
{
    const int w     = threadIdx.x >> 6;
    const int lane  = threadIdx.x & 63;
    const int rbase = blockIdx.x * 32 + w * 8;
#pragma unroll 1
    for (int i = 0; i < 8; ++i) {
        const int r = rbase + i;
        const float* src = cb + (size_t)r * DD + lane * 8;
        float4 a = *reinterpret_cast<const float4*>(src);
        float4 b = *reinterpret_cast<const float4*>(src + 4);
        float v[8] = {a.x, a.y, a.z, a.w, b.x, b.y, b.z, b.w};
        float s2 = 0.f;
        bf16x8 o;
#pragma unroll
        for (int j = 0; j < 8; ++j) { s2 += v[j] * v[j]; o[j] = (short)f2bf(v[j]); }
#pragma unroll
        for (int off = 32; off > 0; off >>= 1) s2 += __shfl_xor(s2, off);
        const int u = lane ^ (r & 7);   // pre-swizzle so linear LDS copy lands swizzled
        *reinterpret_cast<bf16x8*>(cbswz + (size_t)r * DD + u * 8) = o;
        if (lane == 0) esq[r] = s2;
    }
}

// ---------------- K2: scan one codebook quarter for 256 q rows ----------------
__global__ __launch_bounds__(512, 2)
void vq_scan_kernel(const float* __restrict__ h,
                    const unsigned short* __restrict__ cbswz,
                    const float* __restrict__ esqg,
                    uint2* __restrict__ wlist,
                    unsigned int* __restrict__ wcnt)
{
    __shared__ __align__(16) unsigned short sC[2][KC * DD];  // 128 KB dbuf
    __shared__ __align__(16) float sEsq[2][KC];
    __shared__ int sCnt[BQ];

    const int tid  = threadIdx.x;
    const int w    = tid >> 6;          // wave 0..7, owns q rows [w*32, w*32+32)
    const int lane = tid & 63;
    const int c16  = lane & 15;
    const int ub   = lane >> 4;
    const int bid  = blockIdx.x;
    const int kq   = bid & 3;           // codebook quarter
    const int qt   = bid >> 2;          // q tile
    const int qb   = qt * BQ;
    const int g0q  = kq * QCODES;       // first global code of this quarter

    if (tid < BQ) sCnt[tid] = 0;

    // ---- H B-fragments: rows qb+w*32+c16 (A) and +16 (B) ----
    const int qrowA = qb + w * 32 + c16;
    const int dsub  = ub * 8;
    bf16x8 hfA[16], hfB[16];
#pragma unroll
    for (int k = 0; k < 16; ++k) {
        const float* sA = h + (size_t)qrowA * DD + k * 32 + dsub;
        const float* sB = sA + (size_t)16 * DD;
        float4 a0 = *reinterpret_cast<const float4*>(sA);
        float4 a1 = *reinterpret_cast<const float4*>(sA + 4);
        float4 b0 = *reinterpret_cast<const float4*>(sB);
        float4 b1 = *reinterpret_cast<const float4*>(sB + 4);
        bf16x8 fa, fb;
        fa[0]=(short)f2bf(a0.x); fa[1]=(short)f2bf(a0.y); fa[2]=(short)f2bf(a0.z); fa[3]=(short)f2bf(a0.w);
        fa[4]=(short)f2bf(a1.x); fa[5]=(short)f2bf(a1.y); fa[6]=(short)f2bf(a1.z); fa[7]=(short)f2bf(a1.w);
        fb[0]=(short)f2bf(b0.x); fb[1]=(short)f2bf(b0.y); fb[2]=(short)f2bf(b0.z); fb[3]=(short)f2bf(b0.w);
        fb[4]=(short)f2bf(b1.x); fb[5]=(short)f2bf(b1.y); fb[6]=(short)f2bf(b1.z); fb[7]=(short)f2bf(b1.w);
        hfA[k] = fa; hfB[k] = fb;
    }

    const int rowlocA = w * 32 + c16;
    const int rowlocB = rowlocA + 16;
    const size_t lbA  = ((size_t)(qb + rowlocA) * NQUART + kq) * CAP;
    const size_t lbB  = ((size_t)(qb + rowlocB) * NQUART + kq) * CAP;

    float mrunA = -1e38f, mrunB = -1e38f;

    // stage chunk ct into buffer b
    auto stage = [&](int b, int ct) {
        const char* gc = (const char*)cbswz + ((size_t)g0q + (size_t)ct * KC) * (DD * 2);
#pragma unroll
        for (int r = 0; r < 8; ++r)
            gload_lds16(gc + r * 8192 + w * 1024 + lane * 16,
                        (char*)&sC[b][0] + r * 8192 + w * 1024);
        if (w == 0)
            gload_lds4((const char*)(esqg + g0q + ct * KC) + lane * 4,
                       (char*)&sEsq[b][0]);
    };

    // scan chunk in buffer `cur` (codes g0..g0+63 global); append if APPEND
    auto scan_chunk = [&](int cur, int gbase, bool append) {
        const float thrA = mrunA - TH2, thrB = mrunB - TH2;
        float mlA = -1e38f, mlB = -1e38f;
#pragma unroll 1
        for (int rt = 0; rt < 4; ++rt) {
            const int crow = rt * 16 + c16;
            const int swz  = crow & 7;
            const unsigned short* cbase = &sC[cur][crow * DD];
            f32x4 aA0 = {0,0,0,0}, aA1 = {0,0,0,0}, aB0 = {0,0,0,0}, aB1 = {0,0,0,0};
#pragma unroll
            for (int k = 0; k < 16; k += 2) {
                bf16x8 a0 = *reinterpret_cast<const bf16x8*>(&cbase[(((k    ) * 4 + ub) ^ swz) * 8]);
                bf16x8 a1 = *reinterpret_cast<const bf16x8*>(&cbase[(((k + 1) * 4 + ub) ^ swz) * 8]);
                aA0 = __builtin_amdgcn_mfma_f32_16x16x32_bf16(a0, hfA[k],     aA0, 0, 0, 0);
                aB0 = __builtin_amdgcn_mfma_f32_16x16x32_bf16(a0, hfB[k],     aB0, 0, 0, 0);
                aA1 = __builtin_amdgcn_mfma_f32_16x16x32_bf16(a1, hfA[k + 1], aA1, 0, 0, 0);
                aB1 = __builtin_amdgcn_mfma_f32_16x16x32_bf16(a1, hfB[k + 1], aB1, 0, 0, 0);
            }
            const int clocal = rt * 16 + ub * 4;
            f32x4 e4 = *reinterpret_cast<const f32x4*>(&sEsq[cur][clocal]);
            float LvA[4], LvB[4];
#pragma unroll
            for (int r = 0; r < 4; ++r) {
                LvA[r] = (aA0[r] + aA1[r]) * SC_CROSS - e4[r] * SC_ESQ;
                LvB[r] = (aB0[r] + aB1[r]) * SC_CROSS - e4[r] * SC_ESQ;
            }
            mlA = fmaxf(mlA, fmaxf(fmaxf(LvA[0], LvA[1]), fmaxf(LvA[2], LvA[3])));
            mlB = fmaxf(mlB, fmaxf(fmaxf(LvB[0], LvB[1]), fmaxf(LvB[2], LvB[3])));
            if (append) {
                if (LvA[0] > thrA || LvA[1] > thrA || LvA[2] > thrA || LvA[3] > thrA) {
#pragma unroll
                    for (int r = 0; r < 4; ++r)
                        if (LvA[r] > thrA) {
                            int idx = atomicAdd(&sCnt[rowlocA], 1);
                            wlist[lbA + (idx & (CAP - 1))] =
                                make_uint2((unsigned)(gbase + clocal + r), __float_as_uint(LvA[r]));
                        }
                }
                if (LvB[0] > thrB || LvB[1] > thrB || LvB[2] > thrB || LvB[3] > thrB) {
#pragma unroll
                    for (int r = 0; r < 4; ++r)
                        if (LvB[r] > thrB) {
                            int idx = atomicAdd(&sCnt[rowlocB], 1);
                            wlist[lbB + (idx & (CAP - 1))] =
                                make_uint2((unsigned)(gbase + clocal + r), __float_as_uint(LvB[r]));
                        }
                }
            }
        }
        // wave-share the row max across the 4 owning lanes (c16, c16+16, ...)
        mlA = fmaxf(mlA, __shfl_xor(mlA, 16)); mlA = fmaxf(mlA, __shfl_xor(mlA, 32));
        mlB = fmaxf(mlB, __shfl_xor(mlB, 16)); mlB = fmaxf(mlB, __shfl_xor(mlB, 32));
        mrunA = fmaxf(mrunA, mlA);
        mrunB = fmaxf(mrunB, mlB);
    };

    // prologue: stage chunk 0; prime running max with a no-append prepass
    stage(0, 0);
    __syncthreads();
    scan_chunk(0, g0q, false);

    int cur = 0;
    for (int t = 0; t < NCHUNK; ++t) {
        if (t + 1 < NCHUNK) stage(cur ^ 1, t + 1);
        scan_chunk(cur, g0q + t * KC, true);
        __syncthreads();
        cur ^= 1;
    }

    if (tid < BQ) wcnt[(size_t)(qb + tid) * NQUART + kq] = (unsigned)sCnt[tid];
}

// ---------------- K3: merge lists, prune, exact softmax gather ----------------
__global__ __launch_bounds__(512)
void vq_merge_kernel(const float* __restrict__ h,
                     const float* __restrict__ cb,
                     const uint2* __restrict__ wlist,
                     const unsigned int* __restrict__ wcnt,
                     float* __restrict__ out)
{
    const int w    = threadIdx.x >> 6;
    const int lane = threadIdx.x & 63;
    const int qg   = blockIdx.x * 8 + w;

    const int quarter = lane >> 4;      // 4 quarters x 16 slots
    const int slot    = lane & 15;
    const unsigned cq = wcnt[(size_t)qg * NQUART + quarter];
    const bool valid  = slot < (int)min(cq, (unsigned)CAP);

    unsigned codev = 0;
    float L = -1e38f;
    if (valid) {
        uint2 e = wlist[((size_t)qg * NQUART + quarter) * CAP + slot];
        codev = e.x;
        L = __uint_as_float(e.y);
    }
    // wave max of approx logits
    float M = L;
#pragma unroll
    for (int off = 1; off < 64; off <<= 1) M = fmaxf(M, __shfl_xor(M, off));

    unsigned long long mask = __ballot(valid && (L > M - PRUNE));

    float hreg[8];
    const float* hp = h + (size_t)qg * DD + lane * 8;
#pragma unroll
    for (int j = 0; j < 8; ++j) hreg[j] = hp[j];

    float Mex = -1e38f, lsum = 0.f;
    float acc[8] = {0.f,0.f,0.f,0.f,0.f,0.f,0.f,0.f};
#pragma unroll 1
    while (mask) {
        const int s = __builtin_ctzll(mask);
        mask &= mask - 1;
        const int code = __shfl((int)codev, s);
        const float* cp = cb + (size_t)code * DD + lane * 8;
        float c[8];
        float dot = 0.f, s2 = 0.f;
#pragma unroll
        for (int j = 0; j < 8; ++j) {
            c[j] = cp[j];
            dot += hreg[j] * c[j];
            s2  += c[j] * c[j];
        }
#pragma unroll
        for (int off = 32; off > 0; off >>= 1) {
            dot += __shfl_xor(dot, off);
            s2  += __shfl_xor(s2,  off);
        }
        const float Lex = dot * SC_CROSS - s2 * SC_ESQ;   // exact log2-logit
        const float mn  = fmaxf(Mex, Lex);
        const float f   = exp2f(Mex - mn);
        const float wj  = exp2f(Lex - mn);
        lsum = lsum * f + wj;
#pragma unroll
        for (int j = 0; j < 8; ++j) acc[j] = acc[j] * f + wj * c[j];
        Mex = mn;
    }
    const float inv = 1.0f / lsum;
    float* op = out + (size_t)qg * DD + lane * 8;
    float4 o0 = {acc[0]*inv, acc[1]*inv, acc[2]*inv, acc[3]*inv};
    float4 o1 = {acc[4]*inv, acc[5]*inv, acc[6]*inv, acc[7]*inv};
    *reinterpret_cast<float4*>(op)     = o0;
    *reinterpret_cast<float4*>(op + 4) = o1;
}

extern "C" void kernel_launch(void* const* d_in, const int* in_sizes, int n_in,
                              void* d_out, int out_size, void* d_ws, size_t ws_size,
                              hipStream_t stream) {
    const float* h  = (const float*)d_in[0];   // (16384, 512) fp32
    const float* cb = (const float*)d_in[1];   // (8192, 512) fp32
    float* out = (float*)d_out;                // (16384, 512) fp32

    // ws layout: cbswz 8 MB | esq 32 KB | lists 8 MB | counts 256 KB  (~16.3 MB)
    char* p = (char*)d_ws;
    unsigned short* cbswz = (unsigned short*)p;                 p += (size_t)NCODES * DD * 2;
    float*          esq   = (float*)p;                          p += (size_t)NCODES * 4;
    uint2*          wlist = (uint2*)p;                          p += (size_t)16384 * NQUART * CAP * 8;
    unsigned int*   wcnt  = (unsigned int*)p;

    vq_convert_kernel<<<dim3(NCODES / 32), dim3(256), 0, stream>>>(cb, cbswz, esq);
    vq_scan_kernel<<<dim3(256), dim3(512), 0, stream>>>(h, cbswz, esq, wlist, wcnt);
    vq_merge_kernel<<<dim3(16384 / 8), dim3(512), 0, stream>>>(h, cb, wlist, wcnt, out);
}